// Round 6
// baseline (1040.613 us; speedup 1.0000x reference)
//
#include <hip/hip_runtime.h>

// ---------------------------------------------------------------------------
// R6: sdo_bin split into sdo_val (stream+gather, trivially pipelineable) and
// sdo_bin2 (multi-split; rank from pass-A histogram atomic; stage_meta u32
// kills the 9-deep binary search). VGPR=52 in R3/R5 proved the compiler
// de-pipelined the fused kernel. sdo_reduce gets a 2-deep prefetch pipeline
// and will finally be visible in top-5. Path B = R5 fused bin (ws fallback).
// ---------------------------------------------------------------------------

typedef float          f32x2 __attribute__((ext_vector_type(2)));
typedef float          f32x4 __attribute__((ext_vector_type(4)));
typedef unsigned short u16x4 __attribute__((ext_vector_type(4)));

#define SDO_SCALE     8388608.0f   // 2^23 fixed-point scale (fallback path)
#define RSCALE        8192.0f      // 2^13 fixed-point scale (u32 packed path)
#define NBKT_BITS     11           // nodes per bucket = 2048
#define NODES_PER_BKT 2048
#define TILE          16384        // edges per binning block
#define BLOCK_BIN     1024
#define EPT           16           // TILE / BLOCK_BIN
#define NB_MAX        512          // max buckets (1e6/2048 = 489)
#define CAP           68000u      // slots per bucket (mean 65536, ~ +9.6 sigma)
#define EPV           8            // edges per thread in sdo_val

// ---------------- Full (split) path ----------------

// K0: compact x[:,0] into dense x0; init per-bucket cursors.
__global__ void sdo_init(const float* __restrict__ x, float* __restrict__ x0,
                         unsigned int* __restrict__ cursor, int n_nodes, int nb) {
    int i = blockIdx.x * blockDim.x + threadIdx.x;
    if (i < n_nodes) x0[i] = x[4 * i];
    if (i < nb) cursor[i] = (unsigned int)i * CAP;
}

// K1a: pure stream+gather: v[e] = (x0[d]-x0[s])/a. Small reg footprint,
// grid-stride-free (one shot), latency hidden by TLP (many blocks/CU).
__global__ __launch_bounds__(256, 4) void sdo_val(
        const int* __restrict__ src_idx, const int* __restrict__ dst_idx,
        const float* __restrict__ x0, const float* __restrict__ edge_attr,
        float* __restrict__ vtmp, int n_edges) {
    const long long base = (long long)blockIdx.x * (256 * EPV) + threadIdx.x;
    int   d[EPV], s[EPV];
    float a[EPV];
    #pragma unroll
    for (int k = 0; k < EPV; ++k) {
        long long e = base + (long long)k * 256;
        bool ok = (e < n_edges);
        d[k] = ok ? __builtin_nontemporal_load(&dst_idx[e]) : 0;
        s[k] = ok ? __builtin_nontemporal_load(&src_idx[e]) : 0;
        f32x2 a2 = ok ? __builtin_nontemporal_load((const f32x2*)edge_attr + e)
                      : (f32x2){1.0f, 1.0f};
        a[k] = a2.x;
    }
    float gd[EPV], gs[EPV];
    #pragma unroll
    for (int k = 0; k < EPV; ++k) gd[k] = x0[d[k]];
    #pragma unroll
    for (int k = 0; k < EPV; ++k) gs[k] = x0[s[k]];
    #pragma unroll
    for (int k = 0; k < EPV; ++k) {
        long long e = base + (long long)k * 256;
        if (e < n_edges)
            __builtin_nontemporal_store((gd[k] - gs[k]) / a[k], &vtmp[e]);
    }
}

// K1b: multi-split of (dst, v) into bucket-contiguous global regions.
// Rank comes from the pass-A histogram atomic (no second atomic pass);
// stage_meta carries (bucket<<11 | local_idx) so the flush needs no search.
__global__ __launch_bounds__(BLOCK_BIN, 4) void sdo_bin2(
        const int* __restrict__ dst_idx, const float* __restrict__ vtmp,
        float* __restrict__ ebuf_val, unsigned short* __restrict__ ebuf_idx,
        unsigned int* __restrict__ cursor, int n_edges, int nb) {
    __shared__ float        stage_val[TILE];    // 64 KB
    __shared__ unsigned int stage_meta[TILE];   // 64 KB
    __shared__ unsigned int hist[NB_MAX];       //  2 KB each below
    __shared__ unsigned int scanA[NB_MAX];
    __shared__ unsigned int base_l[NB_MAX];
    __shared__ unsigned int base_g[NB_MAX];

    const int tid = threadIdx.x;
    const long long tbase = (long long)blockIdx.x * TILE;

    if (tid < NB_MAX) hist[tid] = 0u;
    __syncthreads();

    // pass A: load dst + v, histogram with rank capture
    int          dreg[EPT];
    float        vreg[EPT];
    unsigned int rreg[EPT];
    #pragma unroll
    for (int k = 0; k < EPT; ++k) {
        long long e = tbase + (long long)k * BLOCK_BIN + tid;
        if (e < n_edges) {
            dreg[k] = __builtin_nontemporal_load(&dst_idx[e]);
            vreg[k] = __builtin_nontemporal_load(&vtmp[e]);
            rreg[k] = atomicAdd(&hist[dreg[k] >> NBKT_BITS], 1u);
        } else {
            dreg[k] = -1;
        }
    }
    __syncthreads();

    // inclusive scan over 512 buckets (guards inside, barriers outside)
    if (tid < NB_MAX) scanA[tid] = hist[tid];
    __syncthreads();
    for (int off = 1; off < NB_MAX; off <<= 1) {
        unsigned int v = 0;
        if (tid < NB_MAX && tid >= off) v = scanA[tid - off];
        __syncthreads();
        if (tid < NB_MAX) scanA[tid] += v;
        __syncthreads();
    }
    if (tid < NB_MAX) {
        base_l[tid] = scanA[tid] - hist[tid];
        unsigned int c = hist[tid];
        base_g[tid] = c ? atomicAdd(&cursor[tid], c) : 0u;
    }
    __syncthreads();

    // pass B: pure stores into staging (slot = base_l[b] + rank)
    #pragma unroll
    for (int k = 0; k < EPT; ++k) {
        int d = dreg[k];
        if (d >= 0) {
            int b = d >> NBKT_BITS;
            unsigned int idx = base_l[b] + rreg[k];
            stage_val[idx]  = vreg[k];
            stage_meta[idx] = ((unsigned int)b << NBKT_BITS)
                            | (unsigned int)(d & (NODES_PER_BKT - 1));
        }
    }
    __syncthreads();

    // flush: 1 meta read gives the bucket; no search chain.
    const unsigned int total = scanA[NB_MAX - 1];
    for (unsigned int j = tid; j < total; j += BLOCK_BIN) {
        unsigned int m = stage_meta[j];
        unsigned int b = m >> NBKT_BITS;
        unsigned int g = base_g[b] + (j - base_l[b]);
        __builtin_nontemporal_store(stage_val[j], &ebuf_val[g]);
        __builtin_nontemporal_store((unsigned short)(m & (NODES_PER_BKT - 1)),
                                    &ebuf_idx[g]);
    }
}

// K2: one block per bucket; packed u32 LDS accumulation (count in low 8 bits,
// 2^13 fixed-point sum in bits 8..31), 2-deep prefetch pipeline, exclusive
// node ownership -> plain stores of the mean.
__global__ __launch_bounds__(1024) void sdo_reduce(
        const float* __restrict__ ebuf_val,
        const unsigned short* __restrict__ ebuf_idx,
        const unsigned int* __restrict__ cursor,
        float* __restrict__ out, int n_nodes) {
    __shared__ unsigned int acc[NODES_PER_BKT];   // 8 KB
    const int b = blockIdx.x;
    const int tid = threadIdx.x;
    acc[tid] = 0u;
    acc[tid + 1024] = 0u;
    __syncthreads();

    const unsigned int beg = (unsigned int)b * CAP;
    const unsigned int end = cursor[b];
    const unsigned int n   = end - beg;
    const unsigned int n4  = n >> 2;

    const f32x4* v4 = (const f32x4*)(ebuf_val + beg);   // beg*4 % 16 == 0
    const u16x4* i4 = (const u16x4*)(ebuf_idx + beg);   // beg*2 %  8 == 0

    // 2-deep software pipeline: prefetch t+1024 while processing t.
    f32x4 va; u16x4 ia;
    unsigned int t = tid;
    if (t < n4) { va = __builtin_nontemporal_load(&v4[t]);
                  ia = __builtin_nontemporal_load(&i4[t]); }
    for (; t < n4; ) {
        unsigned int tn = t + 1024;
        f32x4 vb; u16x4 ib;
        if (tn < n4) { vb = __builtin_nontemporal_load(&v4[tn]);
                       ib = __builtin_nontemporal_load(&i4[tn]); }
        int q0 = __float2int_rn(va.x * RSCALE);
        int q1 = __float2int_rn(va.y * RSCALE);
        int q2 = __float2int_rn(va.z * RSCALE);
        int q3 = __float2int_rn(va.w * RSCALE);
        atomicAdd(&acc[ia.x], ((unsigned int)q0 << 8) + 1u);
        atomicAdd(&acc[ia.y], ((unsigned int)q1 << 8) + 1u);
        atomicAdd(&acc[ia.z], ((unsigned int)q2 << 8) + 1u);
        atomicAdd(&acc[ia.w], ((unsigned int)q3 << 8) + 1u);
        va = vb; ia = ib;
        t = tn;
    }
    // scalar tail
    for (unsigned int j = beg + (n4 << 2) + tid; j < end; j += 1024) {
        float v = ebuf_val[j];
        int d_low = ebuf_idx[j];
        int q = __float2int_rn(v * RSCALE);
        atomicAdd(&acc[d_low], ((unsigned int)q << 8) + 1u);
    }
    __syncthreads();

    const int nbase = b << NBKT_BITS;
    for (int i = tid; i < NODES_PER_BKT; i += 1024) {
        int node = nbase + i;
        if (node < n_nodes) {
            int tt = (int)acc[i];
            int cnt = tt & 0xFF;
            int sf  = tt >> 8;           // arithmetic shift: sign-extends sum
            out[node] = cnt ? ((float)sf / RSCALE) / (float)cnt : 0.0f;
        }
    }
}

// ---------------- Path B: R5 fused bin (if ws too small for vtmp) ----------

__global__ __launch_bounds__(BLOCK_BIN, 4) void sdo_bin_fused(
        const int* __restrict__ src_idx, const int* __restrict__ dst_idx,
        const float* __restrict__ x0, const float* __restrict__ edge_attr,
        float* __restrict__ ebuf_val, unsigned short* __restrict__ ebuf_idx,
        unsigned int* __restrict__ cursor, int n_edges, int nb) {
    __shared__ float        stage_val[TILE];
    __shared__ unsigned int stage_meta[TILE];
    __shared__ unsigned int hist[NB_MAX];
    __shared__ unsigned int scanA[NB_MAX];
    __shared__ unsigned int base_l[NB_MAX];
    __shared__ unsigned int base_g[NB_MAX];

    const int tid = threadIdx.x;
    const long long tbase = (long long)blockIdx.x * TILE;

    if (tid < NB_MAX) hist[tid] = 0u;
    __syncthreads();

    int          dreg[EPT];
    float        vreg[EPT];
    unsigned int rreg[EPT];
    #pragma unroll
    for (int k = 0; k < EPT; ++k) {
        long long e = tbase + (long long)k * BLOCK_BIN + tid;
        if (e < n_edges) {
            int d = __builtin_nontemporal_load(&dst_idx[e]);
            int s = __builtin_nontemporal_load(&src_idx[e]);
            f32x2 a2 = __builtin_nontemporal_load((const f32x2*)edge_attr + e);
            dreg[k] = d;
            vreg[k] = (x0[d] - x0[s]) / a2.x;
            rreg[k] = atomicAdd(&hist[d >> NBKT_BITS], 1u);
        } else {
            dreg[k] = -1;
        }
    }
    __syncthreads();

    if (tid < NB_MAX) scanA[tid] = hist[tid];
    __syncthreads();
    for (int off = 1; off < NB_MAX; off <<= 1) {
        unsigned int v = 0;
        if (tid < NB_MAX && tid >= off) v = scanA[tid - off];
        __syncthreads();
        if (tid < NB_MAX) scanA[tid] += v;
        __syncthreads();
    }
    if (tid < NB_MAX) {
        base_l[tid] = scanA[tid] - hist[tid];
        unsigned int c = hist[tid];
        base_g[tid] = c ? atomicAdd(&cursor[tid], c) : 0u;
    }
    __syncthreads();

    #pragma unroll
    for (int k = 0; k < EPT; ++k) {
        int d = dreg[k];
        if (d >= 0) {
            int b = d >> NBKT_BITS;
            unsigned int idx = base_l[b] + rreg[k];
            stage_val[idx]  = vreg[k];
            stage_meta[idx] = ((unsigned int)b << NBKT_BITS)
                            | (unsigned int)(d & (NODES_PER_BKT - 1));
        }
    }
    __syncthreads();

    const unsigned int total = scanA[NB_MAX - 1];
    for (unsigned int j = tid; j < total; j += BLOCK_BIN) {
        unsigned int m = stage_meta[j];
        unsigned int b = m >> NBKT_BITS;
        unsigned int g = base_g[b] + (j - base_l[b]);
        __builtin_nontemporal_store(stage_val[j], &ebuf_val[g]);
        __builtin_nontemporal_store((unsigned short)(m & (NODES_PER_BKT - 1)),
                                    &ebuf_idx[g]);
    }
}

// ---------------- Path C: packed-atomic fallback ----------------

__global__ void sdo_scatter_packed_strided(const int* __restrict__ src_idx,
                                           const int* __restrict__ dst_idx,
                                           const float* __restrict__ x,
                                           const float* __restrict__ edge_attr,
                                           unsigned long long* __restrict__ packed,
                                           int n_edges) {
    int i = blockIdx.x * blockDim.x + threadIdx.x;
    if (i >= n_edges) return;
    int s = src_idx[i];
    int d = dst_idx[i];
    float e  = edge_attr[2 * i];
    float ld = (x[4 * d] - x[4 * s]) / e;
    long long q = __float2ll_rn(ld * SDO_SCALE);
    atomicAdd(&packed[d], (unsigned long long)((q << 20) + 1));
}

__global__ void sdo_finalize_packed(const unsigned long long* __restrict__ packed,
                                    float* __restrict__ out, int n_nodes) {
    int i = blockIdx.x * blockDim.x + threadIdx.x;
    if (i >= n_nodes) return;
    long long t = (long long)packed[i];
    long long cnt = t & 0xFFFFFLL;
    long long sf  = t >> 20;
    out[i] = (cnt > 0) ? (float)(((double)sf / (double)SDO_SCALE) / (double)cnt) : 0.0f;
}

// ---------------- launch ----------------

extern "C" void kernel_launch(void* const* d_in, const int* in_sizes, int n_in,
                              void* d_out, int out_size, void* d_ws, size_t ws_size,
                              hipStream_t stream) {
    const float* x         = (const float*)d_in[0];   // (N_NODES, 4) fp32
    const int*   edge_idx  = (const int*)d_in[1];     // (2, N_EDGES) int
    const float* edge_attr = (const float*)d_in[2];   // (N_EDGES, 2) fp32

    const int n_nodes = in_sizes[0] / 4;
    const int n_edges = in_sizes[2] / 2;
    const int* src_idx = edge_idx;
    const int* dst_idx = edge_idx + n_edges;
    float* out = (float*)d_out;

    const int nb = (n_nodes + NODES_PER_BKT - 1) >> NBKT_BITS;

    // ws layout: ebuf_val | ebuf_idx | x0 | cursor | vtmp(optional)
    const size_t eval_bytes = (size_t)nb * CAP * sizeof(float);
    const size_t eidx_bytes = (size_t)nb * CAP * sizeof(unsigned short);
    const size_t x0_bytes   = (size_t)n_nodes * sizeof(float);
    const size_t cur_bytes  = (size_t)((nb + 63) & ~63) * sizeof(unsigned int);
    const size_t need_full  = eval_bytes + eidx_bytes + x0_bytes + cur_bytes;
    const size_t vtmp_bytes = (size_t)n_edges * sizeof(float);
    const size_t need_split = need_full + vtmp_bytes;

    const int block = 256;

    if (ws_size >= need_full && nb <= NB_MAX) {
        float* ebuf_val = (float*)d_ws;
        unsigned short* ebuf_idx = (unsigned short*)((char*)d_ws + eval_bytes);
        float* x0 = (float*)((char*)d_ws + eval_bytes + eidx_bytes);
        unsigned int* cursor =
            (unsigned int*)((char*)d_ws + eval_bytes + eidx_bytes + x0_bytes);
        float* vtmp = (float*)((char*)d_ws + need_full);

        const int grid_init = (n_nodes + block - 1) / block;
        sdo_init<<<grid_init, block, 0, stream>>>(x, x0, cursor, n_nodes, nb);

        const int grid_bin = (n_edges + TILE - 1) / TILE;
        if (ws_size >= need_split) {
            const int grid_val = (n_edges + block * EPV - 1) / (block * EPV);
            sdo_val<<<grid_val, block, 0, stream>>>(src_idx, dst_idx, x0,
                                                    edge_attr, vtmp, n_edges);
            sdo_bin2<<<grid_bin, BLOCK_BIN, 0, stream>>>(dst_idx, vtmp,
                                                         ebuf_val, ebuf_idx,
                                                         cursor, n_edges, nb);
        } else {
            sdo_bin_fused<<<grid_bin, BLOCK_BIN, 0, stream>>>(
                src_idx, dst_idx, x0, edge_attr,
                ebuf_val, ebuf_idx, cursor, n_edges, nb);
        }
        sdo_reduce<<<nb, 1024, 0, stream>>>(ebuf_val, ebuf_idx, cursor, out, n_nodes);
    } else {
        unsigned long long* packed = (unsigned long long*)d_ws;   // 8 MB
        (void)hipMemsetAsync(packed, 0, (size_t)n_nodes * sizeof(unsigned long long), stream);
        const int grid_e = (n_edges + block - 1) / block;
        sdo_scatter_packed_strided<<<grid_e, block, 0, stream>>>(
            src_idx, dst_idx, x, edge_attr, packed, n_edges);
        const int grid_n = (n_nodes + block - 1) / block;
        sdo_finalize_packed<<<grid_n, block, 0, stream>>>(packed, out, n_nodes);
    }
}

// Round 7
// 1021.586 us; speedup vs baseline: 1.0186x; 1.0186x over previous
//
#include <hip/hip_runtime.h>

// ---------------------------------------------------------------------------
// R7: sdo_val was TA-bound (divergent-gather address processing ~3.3cyc/lane-
// addr: 250K addrs/CU ~ 345us ~ measured 359us) with ALL other pipes idle.
// TA (gathers) and LDS-split (bin2) use different pipes -> fuse them so they
// overlap, and drop the 256MB vtmp round trip. sdo_bin3 = bin2's improved
// split (rank-from-histogram-atomic, meta flush, no binary search) + inline
// gather/value. init/reduce byte-identical to R6 for clean subtraction.
// ---------------------------------------------------------------------------

typedef float          f32x2 __attribute__((ext_vector_type(2)));
typedef float          f32x4 __attribute__((ext_vector_type(4)));
typedef unsigned short u16x4 __attribute__((ext_vector_type(4)));

#define SDO_SCALE     8388608.0f   // 2^23 fixed-point scale (fallback path)
#define RSCALE        8192.0f      // 2^13 fixed-point scale (u32 packed path)
#define NBKT_BITS     11           // nodes per bucket = 2048
#define NODES_PER_BKT 2048
#define TILE          16384        // edges per binning block
#define BLOCK_BIN     1024
#define EPT           16           // TILE / BLOCK_BIN
#define NB_MAX        512          // max buckets (1e6/2048 = 489)
#define CAP           68000u       // slots per bucket (mean 65439, ~ +10 sigma)

// ---------------- Full path ----------------

// K0: compact x[:,0] into dense x0; init per-bucket cursors.
__global__ void sdo_init(const float* __restrict__ x, float* __restrict__ x0,
                         unsigned int* __restrict__ cursor, int n_nodes, int nb) {
    int i = blockIdx.x * blockDim.x + threadIdx.x;
    if (i < n_nodes) x0[i] = x[4 * i];
    if (i < nb) cursor[i] = (unsigned int)i * CAP;
}

// K1: fused gather + multi-split. Per edge: stream dst/src/attr, gather x0
// (TA pipe) interleaved with histogram/rank LDS atomics (LDS pipe), then
// store into bucket-contiguous staging and flush coalesced (meta: no search).
__global__ __launch_bounds__(BLOCK_BIN, 4) void sdo_bin3(
        const int* __restrict__ src_idx, const int* __restrict__ dst_idx,
        const float* __restrict__ x0, const float* __restrict__ edge_attr,
        float* __restrict__ ebuf_val, unsigned short* __restrict__ ebuf_idx,
        unsigned int* __restrict__ cursor, int n_edges, int nb) {
    __shared__ float        stage_val[TILE];    // 64 KB
    __shared__ unsigned int stage_meta[TILE];   // 64 KB
    __shared__ unsigned int hist[NB_MAX];       //  2 KB each below
    __shared__ unsigned int scanA[NB_MAX];
    __shared__ unsigned int base_l[NB_MAX];
    __shared__ unsigned int base_g[NB_MAX];

    const int tid = threadIdx.x;
    const long long tbase = (long long)blockIdx.x * TILE;

    if (tid < NB_MAX) hist[tid] = 0u;
    __syncthreads();

    // pass A: stream edges, gather x0, compute value, histogram with rank.
    int          dreg[EPT];
    float        vreg[EPT];
    unsigned int rreg[EPT];
    #pragma unroll
    for (int k = 0; k < EPT; ++k) {
        long long e = tbase + (long long)k * BLOCK_BIN + tid;
        if (e < n_edges) {
            int d = __builtin_nontemporal_load(&dst_idx[e]);
            int s = __builtin_nontemporal_load(&src_idx[e]);
            f32x2 a2 = __builtin_nontemporal_load((const f32x2*)edge_attr + e);
            dreg[k] = d;
            vreg[k] = (x0[d] - x0[s]) / a2.x;
            rreg[k] = atomicAdd(&hist[d >> NBKT_BITS], 1u);
        } else {
            dreg[k] = -1;
        }
    }
    __syncthreads();

    // inclusive scan over 512 buckets (guards inside, barriers outside)
    if (tid < NB_MAX) scanA[tid] = hist[tid];
    __syncthreads();
    for (int off = 1; off < NB_MAX; off <<= 1) {
        unsigned int v = 0;
        if (tid < NB_MAX && tid >= off) v = scanA[tid - off];
        __syncthreads();
        if (tid < NB_MAX) scanA[tid] += v;
        __syncthreads();
    }
    if (tid < NB_MAX) {
        base_l[tid] = scanA[tid] - hist[tid];
        unsigned int c = hist[tid];
        base_g[tid] = c ? atomicAdd(&cursor[tid], c) : 0u;
    }
    __syncthreads();

    // pass B: pure stores into staging (slot = base_l[b] + rank)
    #pragma unroll
    for (int k = 0; k < EPT; ++k) {
        int d = dreg[k];
        if (d >= 0) {
            int b = d >> NBKT_BITS;
            unsigned int idx = base_l[b] + rreg[k];
            stage_val[idx]  = vreg[k];
            stage_meta[idx] = ((unsigned int)b << NBKT_BITS)
                            | (unsigned int)(d & (NODES_PER_BKT - 1));
        }
    }
    __syncthreads();

    // flush: 1 meta read gives the bucket; no search chain.
    const unsigned int total = scanA[NB_MAX - 1];
    for (unsigned int j = tid; j < total; j += BLOCK_BIN) {
        unsigned int m = stage_meta[j];
        unsigned int b = m >> NBKT_BITS;
        unsigned int g = base_g[b] + (j - base_l[b]);
        __builtin_nontemporal_store(stage_val[j], &ebuf_val[g]);
        __builtin_nontemporal_store((unsigned short)(m & (NODES_PER_BKT - 1)),
                                    &ebuf_idx[g]);
    }
}

// K2: one block per bucket; packed u32 LDS accumulation (count in low 8 bits,
// 2^13 fixed-point sum in bits 8..31), 2-deep prefetch pipeline, exclusive
// node ownership -> plain stores of the mean. (Byte-identical to R6.)
__global__ __launch_bounds__(1024) void sdo_reduce(
        const float* __restrict__ ebuf_val,
        const unsigned short* __restrict__ ebuf_idx,
        const unsigned int* __restrict__ cursor,
        float* __restrict__ out, int n_nodes) {
    __shared__ unsigned int acc[NODES_PER_BKT];   // 8 KB
    const int b = blockIdx.x;
    const int tid = threadIdx.x;
    acc[tid] = 0u;
    acc[tid + 1024] = 0u;
    __syncthreads();

    const unsigned int beg = (unsigned int)b * CAP;
    const unsigned int end = cursor[b];
    const unsigned int n   = end - beg;
    const unsigned int n4  = n >> 2;

    const f32x4* v4 = (const f32x4*)(ebuf_val + beg);   // beg*4 % 16 == 0
    const u16x4* i4 = (const u16x4*)(ebuf_idx + beg);   // beg*2 %  8 == 0

    // 2-deep software pipeline: prefetch t+1024 while processing t.
    f32x4 va; u16x4 ia;
    unsigned int t = tid;
    if (t < n4) { va = __builtin_nontemporal_load(&v4[t]);
                  ia = __builtin_nontemporal_load(&i4[t]); }
    for (; t < n4; ) {
        unsigned int tn = t + 1024;
        f32x4 vb; u16x4 ib;
        if (tn < n4) { vb = __builtin_nontemporal_load(&v4[tn]);
                       ib = __builtin_nontemporal_load(&i4[tn]); }
        int q0 = __float2int_rn(va.x * RSCALE);
        int q1 = __float2int_rn(va.y * RSCALE);
        int q2 = __float2int_rn(va.z * RSCALE);
        int q3 = __float2int_rn(va.w * RSCALE);
        atomicAdd(&acc[ia.x], ((unsigned int)q0 << 8) + 1u);
        atomicAdd(&acc[ia.y], ((unsigned int)q1 << 8) + 1u);
        atomicAdd(&acc[ia.z], ((unsigned int)q2 << 8) + 1u);
        atomicAdd(&acc[ia.w], ((unsigned int)q3 << 8) + 1u);
        va = vb; ia = ib;
        t = tn;
    }
    // scalar tail
    for (unsigned int j = beg + (n4 << 2) + tid; j < end; j += 1024) {
        float v = ebuf_val[j];
        int d_low = ebuf_idx[j];
        int q = __float2int_rn(v * RSCALE);
        atomicAdd(&acc[d_low], ((unsigned int)q << 8) + 1u);
    }
    __syncthreads();

    const int nbase = b << NBKT_BITS;
    for (int i = tid; i < NODES_PER_BKT; i += 1024) {
        int node = nbase + i;
        if (node < n_nodes) {
            int tt = (int)acc[i];
            int cnt = tt & 0xFF;
            int sf  = tt >> 8;           // arithmetic shift: sign-extends sum
            out[node] = cnt ? ((float)sf / RSCALE) / (float)cnt : 0.0f;
        }
    }
}

// ---------------- Fallback (packed-atomic) path ----------------

__global__ void sdo_scatter_packed_strided(const int* __restrict__ src_idx,
                                           const int* __restrict__ dst_idx,
                                           const float* __restrict__ x,
                                           const float* __restrict__ edge_attr,
                                           unsigned long long* __restrict__ packed,
                                           int n_edges) {
    int i = blockIdx.x * blockDim.x + threadIdx.x;
    if (i >= n_edges) return;
    int s = src_idx[i];
    int d = dst_idx[i];
    float e  = edge_attr[2 * i];
    float ld = (x[4 * d] - x[4 * s]) / e;
    long long q = __float2ll_rn(ld * SDO_SCALE);
    atomicAdd(&packed[d], (unsigned long long)((q << 20) + 1));
}

__global__ void sdo_finalize_packed(const unsigned long long* __restrict__ packed,
                                    float* __restrict__ out, int n_nodes) {
    int i = blockIdx.x * blockDim.x + threadIdx.x;
    if (i >= n_nodes) return;
    long long t = (long long)packed[i];
    long long cnt = t & 0xFFFFFLL;
    long long sf  = t >> 20;
    out[i] = (cnt > 0) ? (float)(((double)sf / (double)SDO_SCALE) / (double)cnt) : 0.0f;
}

// ---------------- launch ----------------

extern "C" void kernel_launch(void* const* d_in, const int* in_sizes, int n_in,
                              void* d_out, int out_size, void* d_ws, size_t ws_size,
                              hipStream_t stream) {
    const float* x         = (const float*)d_in[0];   // (N_NODES, 4) fp32
    const int*   edge_idx  = (const int*)d_in[1];     // (2, N_EDGES) int
    const float* edge_attr = (const float*)d_in[2];   // (N_EDGES, 2) fp32

    const int n_nodes = in_sizes[0] / 4;
    const int n_edges = in_sizes[2] / 2;
    const int* src_idx = edge_idx;
    const int* dst_idx = edge_idx + n_edges;
    float* out = (float*)d_out;

    const int nb = (n_nodes + NODES_PER_BKT - 1) >> NBKT_BITS;

    // ws layout: ebuf_val | ebuf_idx | x0 | cursor
    const size_t eval_bytes = (size_t)nb * CAP * sizeof(float);
    const size_t eidx_bytes = (size_t)nb * CAP * sizeof(unsigned short);
    const size_t x0_bytes   = (size_t)n_nodes * sizeof(float);
    const size_t cur_bytes  = (size_t)((nb + 63) & ~63) * sizeof(unsigned int);
    const size_t need_full  = eval_bytes + eidx_bytes + x0_bytes + cur_bytes;

    const int block = 256;

    if (ws_size >= need_full && nb <= NB_MAX) {
        float* ebuf_val = (float*)d_ws;
        unsigned short* ebuf_idx = (unsigned short*)((char*)d_ws + eval_bytes);
        float* x0 = (float*)((char*)d_ws + eval_bytes + eidx_bytes);
        unsigned int* cursor =
            (unsigned int*)((char*)d_ws + eval_bytes + eidx_bytes + x0_bytes);

        const int grid_init = (n_nodes + block - 1) / block;
        sdo_init<<<grid_init, block, 0, stream>>>(x, x0, cursor, n_nodes, nb);

        const int grid_bin = (n_edges + TILE - 1) / TILE;
        sdo_bin3<<<grid_bin, BLOCK_BIN, 0, stream>>>(src_idx, dst_idx, x0,
                                                     edge_attr, ebuf_val,
                                                     ebuf_idx, cursor,
                                                     n_edges, nb);

        sdo_reduce<<<nb, 1024, 0, stream>>>(ebuf_val, ebuf_idx, cursor, out, n_nodes);
    } else {
        unsigned long long* packed = (unsigned long long*)d_ws;   // 8 MB
        (void)hipMemsetAsync(packed, 0, (size_t)n_nodes * sizeof(unsigned long long), stream);
        const int grid_e = (n_edges + block - 1) / block;
        sdo_scatter_packed_strided<<<grid_e, block, 0, stream>>>(
            src_idx, dst_idx, x, edge_attr, packed, n_edges);
        const int grid_n = (n_nodes + block - 1) / block;
        sdo_finalize_packed<<<grid_n, block, 0, stream>>>(packed, out, n_nodes);
    }
}